// Round 1
// baseline (1201.788 us; speedup 1.0000x reference)
//
#include <hip/hip_runtime.h>
#include <hip/hip_bf16.h>

#define Bb 4
#define Tt 256
#define Uu 128
#define H1 512
#define H2 640
#define Dd 640
#define V1c 1025

typedef __bf16 bf16x8 __attribute__((ext_vector_type(8)));
typedef unsigned short ushort8 __attribute__((ext_vector_type(8)));
typedef float floatx4 __attribute__((ext_vector_type(4)));

static __device__ __forceinline__ unsigned short f2bf(float x) {
    union { float f; unsigned u; } a; a.f = x;
    unsigned r = a.u + 0x7fffu + ((a.u >> 16) & 1u);
    return (unsigned short)(r >> 16);
}

// out[b, t, d] = sum_h in[b*H*Tdim + h*Tdim + t] * W[h*Dd + d] + bias[d]
// one block per (b, 4 consecutive t), 640 threads = d
__global__ __launch_bounds__(640) void fg_gemm(const float* __restrict__ in,
                                               const float* __restrict__ W,
                                               const float* __restrict__ bias,
                                               float* __restrict__ out,
                                               int H, int Tdim) {
    int d = threadIdx.x;
    int tBlocks = Tdim >> 2;
    int b = blockIdx.x / tBlocks;
    int t0 = (blockIdx.x % tBlocks) << 2;
    const float* inB = in + (size_t)b * H * Tdim + t0;
    float a0 = 0.f, a1 = 0.f, a2 = 0.f, a3 = 0.f;
    for (int h = 0; h < H; ++h) {
        float w = W[(size_t)h * Dd + d];
        const float* e = inB + (size_t)h * Tdim;
        a0 += e[0] * w; a1 += e[1] * w; a2 += e[2] * w; a3 += e[3] * w;
    }
    float bv = bias[d];
    float* o = out + ((size_t)b * Tdim + t0) * Dd + d;
    o[0] = a0 + bv; o[Dd] = a1 + bv; o[2 * Dd] = a2 + bv; o[3 * Dd] = a3 + bv;
}

// Wb[v][d] = bf16(W_out[d][v]) for v<1024 ; wtail[d] = W_out[d][1024]
__global__ __launch_bounds__(256) void conv_wout(const float* __restrict__ Wout,
                                                 unsigned short* __restrict__ Wb,
                                                 float* __restrict__ wtail) {
    __shared__ float tile[32][33];
    int tx = threadIdx.x & 31, ty = threadIdx.x >> 5;  // ty 0..7
    int vb = (blockIdx.x & 31) * 32;   // 32 v-tiles
    int db = (blockIdx.x >> 5) * 32;   // 20 d-tiles
    #pragma unroll
    for (int j = 0; j < 4; ++j) {
        int d = db + ty + 8 * j;
        tile[ty + 8 * j][tx] = Wout[(size_t)d * V1c + vb + tx];
    }
    __syncthreads();
    #pragma unroll
    for (int j = 0; j < 4; ++j) {
        int v = vb + ty + 8 * j;
        Wb[(size_t)v * Dd + db + tx] = f2bf(tile[tx][ty + 8 * j]);
    }
    if (blockIdx.x == 0) {
        for (int d = threadIdx.x; d < Dd; d += 256) wtail[d] = Wout[(size_t)d * V1c + 1024];
    }
}

// Fused: h = relu(f_row + g_row) -> logits = h*Wb + b_out -> log_softmax -> out
// block: 512 threads (8 waves). 64 rows (fixed b,t ; u0..u0+63) x 1025 cols.
__global__ __launch_bounds__(512) void joint_main(const float* __restrict__ f,
                                                  const float* __restrict__ g,
                                                  const unsigned short* __restrict__ Wb,
                                                  const float* __restrict__ wtail,
                                                  const float* __restrict__ b_out,
                                                  float* __restrict__ out) {
    __shared__ unsigned short hlds[64 * 328];  // 64 rows x 320 bf16 (one K-half), pad->328
    __shared__ float sPart[8 * 64];
    __shared__ float sRed[64];
    __shared__ float sTail[64];

    const int tid = threadIdx.x;
    const int l = tid & 63;
    const int w = tid >> 6;       // wave 0..7
    const int l15 = l & 15;
    const int lg = l >> 4;        // 0..3

    const int blk = blockIdx.x;   // B*T*2 = 2048
    const int uhalf = blk & 1;
    const int t = (blk >> 1) & 255;
    const int b = blk >> 9;
    const int u0 = uhalf * 64;
    const size_t fbase = ((size_t)b * Tt + t) * Dd;
    const size_t gbase = ((size_t)b * Uu + u0) * Dd;
    const size_t rowbase = (size_t)(b * Tt + t) * Uu + u0;

    // ---- tail column (v=1024): wave w handles rows 8w..8w+7 ----
    for (int rr = 0; rr < 8; ++rr) {
        int row = w * 8 + rr;
        const float* fr = f + fbase;
        const float* gr = g + gbase + (size_t)row * Dd;
        float acc = 0.f;
        #pragma unroll
        for (int j = 0; j < 10; ++j) {
            int d = l + 64 * j;
            float h = fr[d] + gr[d];
            h = h > 0.f ? h : 0.f;
            acc += h * wtail[d];
        }
        #pragma unroll
        for (int m = 32; m >= 1; m >>= 1) acc += __shfl_xor(acc, m);
        if (l == 0) sTail[row] = acc + b_out[1024];
    }

    // ---- accumulators: 4 m-tiles x 8 n-tiles ----
    floatx4 acc[4][8];
    #pragma unroll
    for (int i = 0; i < 4; ++i)
        #pragma unroll
        for (int j = 0; j < 8; ++j) acc[i][j] = (floatx4){0.f, 0.f, 0.f, 0.f};

    const int cb = w * 128;  // this wave's column base
    const unsigned short* bptr = Wb + (size_t)(cb + l15) * Dd + lg * 8;

    for (int half = 0; half < 2; ++half) {
        __syncthreads();
        const int dhb = half * 320;
        // stage h panel: 64 rows x 320 bf16 (as 160 dwords/row, stride 164)
        #pragma unroll
        for (int j = 0; j < 20; ++j) {
            int p = tid + 512 * j;     // 0..10239
            int row = p / 160;
            int c = p - row * 160;
            int d = dhb + 2 * c;
            float2 fv = *(const float2*)(f + fbase + d);
            float2 gv = *(const float2*)(g + gbase + (size_t)row * Dd + d);
            float h0 = fv.x + gv.x; h0 = h0 > 0.f ? h0 : 0.f;
            float h1 = fv.y + gv.y; h1 = h1 > 0.f ? h1 : 0.f;
            unsigned pack = (unsigned)f2bf(h0) | ((unsigned)f2bf(h1) << 16);
            *(unsigned*)(&hlds[row * 328 + 2 * c]) = pack;
        }
        __syncthreads();
        // K loop: 10 steps of 32
        for (int ks = 0; ks < 10; ++ks) {
            bf16x8 afrag[4];
            #pragma unroll
            for (int mt = 0; mt < 4; ++mt) {
                ushort8 av = *(const ushort8*)(&hlds[(mt * 16 + l15) * 328 + ks * 32 + lg * 8]);
                afrag[mt] = __builtin_bit_cast(bf16x8, av);
            }
            #pragma unroll
            for (int nt = 0; nt < 8; ++nt) {
                ushort8 bv = *(const ushort8*)(bptr + (size_t)nt * 16 * Dd + dhb + ks * 32);
                bf16x8 bfrag = __builtin_bit_cast(bf16x8, bv);
                #pragma unroll
                for (int mt = 0; mt < 4; ++mt) {
                    acc[mt][nt] = __builtin_amdgcn_mfma_f32_16x16x32_bf16(
                        afrag[mt], bfrag, acc[mt][nt], 0, 0, 0);
                }
            }
        }
    }
    __syncthreads();

    // ---- + b_out ----
    #pragma unroll
    for (int nt = 0; nt < 8; ++nt) {
        float bo = b_out[cb + nt * 16 + l15];
        #pragma unroll
        for (int mt = 0; mt < 4; ++mt)
            #pragma unroll
            for (int r = 0; r < 4; ++r) acc[mt][nt][r] += bo;
    }

    // ---- row max (per wave over its 128 cols, then combine) ----
    #pragma unroll
    for (int mt = 0; mt < 4; ++mt) {
        #pragma unroll
        for (int r = 0; r < 4; ++r) {
            float m = acc[mt][0][r];
            #pragma unroll
            for (int nt = 1; nt < 8; ++nt) m = fmaxf(m, acc[mt][nt][r]);
            #pragma unroll
            for (int msk = 1; msk < 16; msk <<= 1) m = fmaxf(m, __shfl_xor(m, msk));
            if (l15 == 0) sPart[w * 64 + mt * 16 + lg * 4 + r] = m;
        }
    }
    __syncthreads();
    if (tid < 64) {
        float m = sTail[tid];
        #pragma unroll
        for (int ww = 0; ww < 8; ++ww) m = fmaxf(m, sPart[ww * 64 + tid]);
        sRed[tid] = m;
    }
    __syncthreads();

    // ---- sum exp ----
    #pragma unroll
    for (int mt = 0; mt < 4; ++mt) {
        #pragma unroll
        for (int r = 0; r < 4; ++r) {
            int row = mt * 16 + lg * 4 + r;
            float mx = sRed[row];
            float s = 0.f;
            #pragma unroll
            for (int nt = 0; nt < 8; ++nt) s += __expf(acc[mt][nt][r] - mx);
            #pragma unroll
            for (int msk = 1; msk < 16; msk <<= 1) s += __shfl_xor(s, msk);
            if (l15 == 0) sPart[w * 64 + row] = s;
        }
    }
    __syncthreads();
    if (tid < 64) {
        float mx = sRed[tid];
        float s = __expf(sTail[tid] - mx);
        #pragma unroll
        for (int ww = 0; ww < 8; ++ww) s += sPart[ww * 64 + tid];
        sRed[tid] = mx + logf(s);   // lse
    }
    __syncthreads();

    // ---- write ----
    #pragma unroll
    for (int mt = 0; mt < 4; ++mt) {
        #pragma unroll
        for (int nt = 0; nt < 8; ++nt) {
            #pragma unroll
            for (int r = 0; r < 4; ++r) {
                int row = mt * 16 + lg * 4 + r;
                int col = cb + nt * 16 + l15;
                out[(rowbase + row) * (size_t)V1c + col] = acc[mt][nt][r] - sRed[row];
            }
        }
    }
    if (tid < 64) {
        out[(rowbase + tid) * (size_t)V1c + 1024] = sTail[tid] - sRed[tid];
    }
}

extern "C" void kernel_launch(void* const* d_in, const int* in_sizes, int n_in,
                              void* d_out, int out_size, void* d_ws, size_t ws_size,
                              hipStream_t stream) {
    const float* enc   = (const float*)d_in[0];
    const float* pred  = (const float*)d_in[1];
    const float* Wenc  = (const float*)d_in[2];
    const float* benc  = (const float*)d_in[3];
    const float* Wpred = (const float*)d_in[4];
    const float* bpred = (const float*)d_in[5];
    const float* Wout  = (const float*)d_in[6];
    const float* bout  = (const float*)d_in[7];

    float* f = (float*)d_ws;                         // 4*256*640 = 655360 f32
    float* g = f + (size_t)Bb * Tt * Dd;             // 4*128*640 = 327680 f32
    unsigned short* Wb = (unsigned short*)(g + (size_t)Bb * Uu * Dd);  // 1024*640 bf16
    float* wtail = (float*)(Wb + 1024 * Dd);         // 640 f32

    fg_gemm<<<Bb * Tt / 4, 640, 0, stream>>>(enc, Wenc, benc, f, H1, Tt);
    fg_gemm<<<Bb * Uu / 4, 640, 0, stream>>>(pred, Wpred, bpred, g, H2, Uu);
    conv_wout<<<640, 256, 0, stream>>>(Wout, Wb, wtail);
    joint_main<<<Bb * Tt * 2, 512, 0, stream>>>(f, g, Wb, wtail, bout, (float*)d_out);
}

// Round 2
// 541.190 us; speedup vs baseline: 2.2206x; 2.2206x over previous
//
#include <hip/hip_runtime.h>
#include <hip/hip_bf16.h>

#define Bb 4
#define Tt 256
#define Uu 128
#define H1 512
#define H2 640
#define Dd 640
#define V1c 1025

typedef __bf16 bf16x8 __attribute__((ext_vector_type(8)));
typedef unsigned short ushort8 __attribute__((ext_vector_type(8)));
typedef unsigned short ushort4v __attribute__((ext_vector_type(4)));
typedef float floatx4 __attribute__((ext_vector_type(4)));

static __device__ __forceinline__ unsigned short f2bf(float x) {
    union { float f; unsigned u; } a; a.f = x;
    unsigned r = a.u + 0x7fffu + ((a.u >> 16) & 1u);
    return (unsigned short)(r >> 16);
}
static __device__ __forceinline__ float bf2f(unsigned short x) {
    union { unsigned u; float f; } a; a.u = ((unsigned)x) << 16; return a.f;
}

// ---------------- f and g linear layers, fused in one launch ----------------
// blocks [0,128): f = enc^T * W_enc + b_enc   (H=512, Tdim=256, t-tile 8)
// blocks [128,192): g = pred^T * W_pred + b_pred (H=640, Tdim=128, t-tile 8)
__global__ __launch_bounds__(640) void fg_fused(const float* __restrict__ enc,
                                                const float* __restrict__ Wenc,
                                                const float* __restrict__ benc,
                                                float* __restrict__ f,
                                                const float* __restrict__ pred,
                                                const float* __restrict__ Wpred,
                                                const float* __restrict__ bpred,
                                                float* __restrict__ g) {
    __shared__ float s[640 * 8];
    const bool isF = blockIdx.x < 128;
    const float* in   = isF ? enc : pred;
    const float* W    = isF ? Wenc : Wpred;
    const float* bias = isF ? benc : bpred;
    float* out        = isF ? f : g;
    const int H    = isF ? H1 : H2;
    const int Tdim = isF ? Tt : Uu;
    const int blk  = isF ? (int)blockIdx.x : (int)blockIdx.x - 128;
    const int tBlocks = Tdim >> 3;
    const int b  = blk / tBlocks;
    const int t0 = (blk % tBlocks) << 3;
    const float* inB = in + (size_t)b * H * Tdim + t0;
    const int tid = threadIdx.x;

    for (int h = tid; h < H; h += 640) {
        float4 v0 = *(const float4*)(inB + (size_t)h * Tdim);
        float4 v1 = *(const float4*)(inB + (size_t)h * Tdim + 4);
        *(float4*)(&s[h * 8])     = v0;
        *(float4*)(&s[h * 8 + 4]) = v1;
    }
    __syncthreads();

    const int d = tid;
    float acc[8];
    #pragma unroll
    for (int j = 0; j < 8; ++j) acc[j] = 0.f;
    #pragma unroll 4
    for (int h = 0; h < H; ++h) {
        float w = W[(size_t)h * Dd + d];
        float4 s0 = *(const float4*)(&s[h * 8]);
        float4 s1 = *(const float4*)(&s[h * 8 + 4]);
        acc[0] += s0.x * w; acc[1] += s0.y * w; acc[2] += s0.z * w; acc[3] += s0.w * w;
        acc[4] += s1.x * w; acc[5] += s1.y * w; acc[6] += s1.z * w; acc[7] += s1.w * w;
    }
    float bv = bias[d];
    float* o = out + ((size_t)b * Tdim + t0) * Dd + d;
    #pragma unroll
    for (int j = 0; j < 8; ++j) o[(size_t)j * Dd] = acc[j] + bv;
}

// Wb[v][d] = bf16(W_out[d][v]) for v<1024 ; wtail[d] = W_out[d][1024]
__global__ __launch_bounds__(256) void conv_wout(const float* __restrict__ Wout,
                                                 unsigned short* __restrict__ Wb,
                                                 float* __restrict__ wtail) {
    __shared__ float tile[32][33];
    int tx = threadIdx.x & 31, ty = threadIdx.x >> 5;
    int vb = (blockIdx.x & 31) * 32;
    int db = (blockIdx.x >> 5) * 32;
    #pragma unroll
    for (int j = 0; j < 4; ++j) {
        int dd = db + ty + 8 * j;
        tile[ty + 8 * j][tx] = Wout[(size_t)dd * V1c + vb + tx];
    }
    __syncthreads();
    #pragma unroll
    for (int j = 0; j < 4; ++j) {
        int v = vb + ty + 8 * j;
        Wb[(size_t)v * Dd + db + tx] = f2bf(tile[tx][ty + 8 * j]);
    }
    if (blockIdx.x == 0) {
        for (int dd = threadIdx.x; dd < Dd; dd += 256) wtail[dd] = Wout[(size_t)dd * V1c + 1024];
    }
}

// ---------------- fused joint + log-softmax ----------------
// 2048 blocks x 512 thr. Block: 64 rows (b,t fixed; 64 consecutive u) x 1025 cols.
__global__ __launch_bounds__(512, 2) void joint_main(const float* __restrict__ f,
                                                     const float* __restrict__ g,
                                                     const unsigned short* __restrict__ Wb,
                                                     const float* __restrict__ wtail,
                                                     const float* __restrict__ b_out,
                                                     float* __restrict__ out) {
    __shared__ union UU {
        struct { unsigned short hlds[64 * 328]; float wtld[640]; } a;  // 44544 B
        float sOut[16 * 1026];                                         // 65664 B
    } u;
    __shared__ float sPart[8 * 64];
    __shared__ float sRed[64];
    __shared__ float sTail[64];

    const int tid = threadIdx.x;
    const int l = tid & 63;
    const int w = tid >> 6;
    const int l15 = l & 15;
    const int lg = l >> 4;

    const int blk = blockIdx.x;
    const int uhalf = blk & 1;
    const int t = (blk >> 1) & 255;
    const int b = blk >> 9;
    const int u0 = uhalf * 64;
    const size_t fbase = ((size_t)b * Tt + t) * Dd;
    const size_t gbase = ((size_t)b * Uu + u0) * Dd;
    const size_t rowbase = (size_t)(b * Tt + t) * Uu + u0;

    // stage wtail (fp32) into LDS
    for (int i = tid; i < Dd; i += 512) u.a.wtld[i] = wtail[i];

    floatx4 acc[4][8];
    #pragma unroll
    for (int i = 0; i < 4; ++i)
        #pragma unroll
        for (int j = 0; j < 8; ++j) acc[i][j] = (floatx4){0.f, 0.f, 0.f, 0.f};

    const unsigned short* __restrict__ bptr = Wb + (size_t)(w * 128 + l15) * Dd + lg * 8;
    float tailAcc = 0.f;
    const int srow = w * 8 + (l >> 3);   // row this lane helps with for the tail col
    const int ssub = l & 7;

    for (int half = 0; half < 2; ++half) {
        const int dhb = half * 320;
        __syncthreads();   // hlds free (covers wtld staging on first iter)
        // ---- stage h = relu(f+g) panel: 64 rows x 320 cols bf16 ----
        {
            const int row = tid >> 3;
            #pragma unroll
            for (int j = 0; j < 10; ++j) {
                int c4 = (tid & 7) + 8 * j;          // float4 slot 0..79
                int d = dhb + c4 * 4;
                float4 fv = *(const float4*)(f + fbase + d);
                float4 gv = *(const float4*)(g + gbase + (size_t)row * Dd + d);
                float h0 = fv.x + gv.x; h0 = h0 > 0.f ? h0 : 0.f;
                float h1 = fv.y + gv.y; h1 = h1 > 0.f ? h1 : 0.f;
                float h2 = fv.z + gv.z; h2 = h2 > 0.f ? h2 : 0.f;
                float h3 = fv.w + gv.w; h3 = h3 > 0.f ? h3 : 0.f;
                ushort4v pk;
                pk.x = f2bf(h0); pk.y = f2bf(h1); pk.z = f2bf(h2); pk.w = f2bf(h3);
                *(ushort4v*)(&u.a.hlds[row * 328 + c4 * 4]) = pk;
            }
        }
        __syncthreads();

        // ---- K loop: 10 steps of 32, B double-buffered in regs ----
        ushort8 Bbuf[2][8];
        #pragma unroll
        for (int nt = 0; nt < 8; ++nt)
            Bbuf[0][nt] = *(const ushort8*)(bptr + (size_t)nt * 16 * Dd + dhb);
        #pragma unroll
        for (int ks = 0; ks < 10; ++ks) {
            if (ks < 9) {
                #pragma unroll
                for (int nt = 0; nt < 8; ++nt)
                    Bbuf[(ks + 1) & 1][nt] =
                        *(const ushort8*)(bptr + (size_t)nt * 16 * Dd + dhb + (ks + 1) * 32);
            }
            bf16x8 afrag[4];
            #pragma unroll
            for (int mt = 0; mt < 4; ++mt) {
                ushort8 av = *(const ushort8*)(&u.a.hlds[(mt * 16 + l15) * 328 + ks * 32 + lg * 8]);
                afrag[mt] = __builtin_bit_cast(bf16x8, av);
            }
            #pragma unroll
            for (int nt = 0; nt < 8; ++nt) {
                bf16x8 bfrag = __builtin_bit_cast(bf16x8, Bbuf[ks & 1][nt]);
                #pragma unroll
                for (int mt = 0; mt < 4; ++mt) {
                    acc[mt][nt] = __builtin_amdgcn_mfma_f32_16x16x32_bf16(
                        afrag[mt], bfrag, acc[mt][nt], 0, 0, 0);
                }
            }
        }

        // ---- tail column partial: dot(h_row, wtail) from LDS ----
        #pragma unroll
        for (int j = 0; j < 10; ++j) {
            int c4 = ssub + 8 * j;
            ushort4v hv = *(const ushort4v*)(&u.a.hlds[srow * 328 + c4 * 4]);
            float4 wv = *(const float4*)(&u.a.wtld[dhb + c4 * 4]);
            tailAcc += bf2f(hv.x) * wv.x + bf2f(hv.y) * wv.y +
                       bf2f(hv.z) * wv.z + bf2f(hv.w) * wv.w;
        }
    }

    // reduce tail across the 8 sub-lanes of each row
    tailAcc += __shfl_xor(tailAcc, 1);
    tailAcc += __shfl_xor(tailAcc, 2);
    tailAcc += __shfl_xor(tailAcc, 4);
    if (ssub == 0) sTail[srow] = tailAcc + b_out[1024];

    // ---- + b_out ----
    #pragma unroll
    for (int nt = 0; nt < 8; ++nt) {
        float bo = b_out[w * 128 + nt * 16 + l15];
        #pragma unroll
        for (int mt = 0; mt < 4; ++mt)
            #pragma unroll
            for (int r = 0; r < 4; ++r) acc[mt][nt][r] += bo;
    }

    // ---- row max ----
    #pragma unroll
    for (int mt = 0; mt < 4; ++mt) {
        #pragma unroll
        for (int r = 0; r < 4; ++r) {
            float m = acc[mt][0][r];
            #pragma unroll
            for (int nt = 1; nt < 8; ++nt) m = fmaxf(m, acc[mt][nt][r]);
            #pragma unroll
            for (int msk = 1; msk < 16; msk <<= 1) m = fmaxf(m, __shfl_xor(m, msk));
            if (l15 == 0) sPart[w * 64 + mt * 16 + lg * 4 + r] = m;
        }
    }
    __syncthreads();
    if (tid < 64) {
        float m = sTail[tid];
        #pragma unroll
        for (int ww = 0; ww < 8; ++ww) m = fmaxf(m, sPart[ww * 64 + tid]);
        sRed[tid] = m;
    }
    __syncthreads();

    // ---- sum exp ----
    #pragma unroll
    for (int mt = 0; mt < 4; ++mt) {
        #pragma unroll
        for (int r = 0; r < 4; ++r) {
            int row = mt * 16 + lg * 4 + r;
            float mx = sRed[row];
            float sv = 0.f;
            #pragma unroll
            for (int nt = 0; nt < 8; ++nt) sv += __expf(acc[mt][nt][r] - mx);
            #pragma unroll
            for (int msk = 1; msk < 16; msk <<= 1) sv += __shfl_xor(sv, msk);
            if (l15 == 0) sPart[w * 64 + row] = sv;
        }
    }
    __syncthreads();
    if (tid < 64) {
        float mx = sRed[tid];
        float sv = __expf(sTail[tid] - mx);
        #pragma unroll
        for (int ww = 0; ww < 8; ++ww) sv += sPart[ww * 64 + tid];
        sRed[tid] = mx + logf(sv);  // lse
    }
    __syncthreads();   // sRed ready; hlds/wtld dead -> sOut aliasing OK

    // ---- write: 4 groups of 16 rows, staged through LDS for coalescing ----
    for (int grp = 0; grp < 4; ++grp) {
        // dump this group's values into sOut[16][1026]
        #pragma unroll
        for (int nt = 0; nt < 8; ++nt) {
            #pragma unroll
            for (int r = 0; r < 4; ++r) {
                int r16 = lg * 4 + r;
                u.sOut[r16 * 1026 + w * 128 + nt * 16 + l15] =
                    acc[grp][nt][r] - sRed[grp * 16 + r16];
            }
        }
        if (tid < 16) u.sOut[tid * 1026 + 1024] = sTail[grp * 16 + tid] - sRed[grp * 16 + tid];
        __syncthreads();
        // stream 16*1025 contiguous floats
        float* outp = out + (rowbase + grp * 16) * (size_t)V1c;
        int i = tid, rr = 0;
        for (int k = 0; k < 33; ++k) {
            if (i < 16 * 1025) __builtin_nontemporal_store(u.sOut[i + rr], &outp[i]);
            i += 512;
            if (i >= (rr + 1) * 1025) ++rr;
        }
        __syncthreads();   // sOut free for next group
    }
}

extern "C" void kernel_launch(void* const* d_in, const int* in_sizes, int n_in,
                              void* d_out, int out_size, void* d_ws, size_t ws_size,
                              hipStream_t stream) {
    const float* enc   = (const float*)d_in[0];
    const float* pred  = (const float*)d_in[1];
    const float* Wenc  = (const float*)d_in[2];
    const float* benc  = (const float*)d_in[3];
    const float* Wpred = (const float*)d_in[4];
    const float* bpred = (const float*)d_in[5];
    const float* Wout  = (const float*)d_in[6];
    const float* bout  = (const float*)d_in[7];

    float* f = (float*)d_ws;                          // 4*256*640 f32
    float* g = f + (size_t)Bb * Tt * Dd;              // 4*128*640 f32
    unsigned short* Wb = (unsigned short*)(g + (size_t)Bb * Uu * Dd);  // 1024*640 bf16
    float* wtail = (float*)(Wb + 1024 * Dd);          // 640 f32

    fg_fused<<<192, 640, 0, stream>>>(enc, Wenc, benc, f, pred, Wpred, bpred, g);
    conv_wout<<<640, 256, 0, stream>>>(Wout, Wb, wtail);
    joint_main<<<Bb * Tt * 2, 512, 0, stream>>>(f, g, Wb, wtail, bout, (float*)d_out);
}